// Round 1
// baseline (33823.407 us; speedup 1.0000x reference)
//
#include <hip/hip_runtime.h>
#include <cstdint>

#define D_MODEL 1024
#define NHEAD   16
#define NLAYER  6
#define DIM_FF  4096
#define SEQ_B   8
#define SEQ_L   1024
#define TOKENS  (SEQ_B*SEQ_L)   // 8192

typedef __bf16 v8bf __attribute__((ext_vector_type(8)));
typedef float  v4f  __attribute__((ext_vector_type(4)));

__device__ __forceinline__ unsigned short f2bf(float f) {
  unsigned int u = __float_as_uint(f);
  u += 0x7fffu + ((u >> 16) & 1u);      // round-to-nearest-even
  return (unsigned short)(u >> 16);
}

// ---------------- weight fp32 -> bf16 ----------------
__global__ __launch_bounds__(256) void f2b_kernel(const float* __restrict__ in,
                                                  unsigned short* __restrict__ out, long n) {
  long i = (long)blockIdx.x * 256 + threadIdx.x;
  long stride = (long)gridDim.x * 256;
  for (; i < n; i += stride) out[i] = f2bf(in[i]);
}

// ---------------- embedding ----------------
__global__ __launch_bounds__(256) void embed_kernel(const int* __restrict__ ids,
    const float* __restrict__ tok, const float* __restrict__ pos,
    float* __restrict__ X, unsigned short* __restrict__ Xb) {
  long i = (long)blockIdx.x * 256 + threadIdx.x;   // over TOKENS*D_MODEL
  int d = (int)(i & (D_MODEL - 1));
  long bl = i >> 10;
  int l = (int)(bl & (SEQ_L - 1));
  int id = ids[bl];
  float v = tok[(long)id * D_MODEL + d] + pos[(long)l * D_MODEL + d];
  X[i] = v; Xb[i] = f2bf(v);
}

// ---------------- GEMM: C[M,N] = A[M,K] @ W[N,K]^T + bias ----------------
// A,W bf16; accum fp32. ACT: 0 none, 1 exact gelu.
// grid = (N/64, M/16); 4 waves per block, wave w -> n-tile blockIdx.x*4+w.
template<int ACT>
__global__ __launch_bounds__(256) void gemm_bt(
    const unsigned short* __restrict__ A,
    const unsigned short* __restrict__ W,
    const float* __restrict__ bias,
    float* __restrict__ Cf, unsigned short* __restrict__ Cb,
    int M, int N, int K) {
  int wave = threadIdx.x >> 6, lane = threadIdx.x & 63;
  int row = lane & 15, quad = lane >> 4;
  int m0 = blockIdx.y * 16;
  int n0 = blockIdx.x * 64 + wave * 16;
  const unsigned short* Ap = A + (long)(m0 + row) * K + quad * 8;
  const unsigned short* Wp = W + (long)(n0 + row) * K + quad * 8;
  v4f acc = {0.f, 0.f, 0.f, 0.f};
  #pragma unroll 4
  for (int k = 0; k < K; k += 32) {
    v8bf a = *(const v8bf*)(Ap + k);
    v8bf b = *(const v8bf*)(Wp + k);
    acc = __builtin_amdgcn_mfma_f32_16x16x32_bf16(a, b, acc, 0, 0, 0);
  }
  int cn = n0 + row;
  float bv = bias[cn];
  long base = (long)(m0 + quad * 4) * N + cn;
  #pragma unroll
  for (int r = 0; r < 4; ++r) {
    float v = acc[r] + bv;
    if (ACT == 1) v = 0.5f * v * (1.f + erff(v * 0.70710678118f));
    if (Cf) Cf[base + (long)r * N] = v;
    if (Cb) Cb[base + (long)r * N] = f2bf(v);
  }
}

// ---------------- attention (flash-style, fp32 VALU) ----------------
// grid = (L/64, NHEAD, B), block = 256 (4 waves, 16 queries each).
#define LPAD 65
__global__ __launch_bounds__(256) void attn_kernel(
    const float* __restrict__ QKV,      // (B*L, 3072): q|k|v
    const int* __restrict__ ids,
    unsigned short* __restrict__ Ob) {  // (B*L, 1024) bf16
  __shared__ float Qs[64][LPAD];
  __shared__ float Ks[64][LPAD];
  __shared__ float Vs[64][LPAD];
  int tid = threadIdx.x;
  int wave = tid >> 6, lane = tid & 63;
  int ql = lane & 15, dg = lane >> 4;
  int qw = wave * 16 + ql;              // query row within the 64-tile
  int b = blockIdx.z, h = blockIdx.y;
  int q0 = blockIdx.x * 64;
  const float* base = QKV + (long)b * SEQ_L * 3072 + h * 64;
  for (int i = tid; i < 64 * 64; i += 256) {
    int r = i >> 6, c = i & 63;
    Qs[r][c] = base[(long)(q0 + r) * 3072 + c];
  }
  float m_run = -1e30f, l_run = 0.f;
  float O[16];
  #pragma unroll
  for (int t = 0; t < 16; ++t) O[t] = 0.f;
  const int* idrow = ids + b * SEQ_L;

  for (int k0 = 0; k0 < SEQ_L; k0 += 64) {
    __syncthreads();   // previous chunk fully consumed (also orders Q load)
    for (int i = tid; i < 64 * 64; i += 256) {
      int r = i >> 6, c = i & 63;
      Ks[r][c] = base[1024 + (long)(k0 + r) * 3072 + c];
      Vs[r][c] = base[2048 + (long)(k0 + r) * 3072 + c];
    }
    __syncthreads();
    // scores: lane (ql,dg) -> query qw, keys j = dg*16+t
    float s[16];
    #pragma unroll
    for (int t = 0; t < 16; ++t) s[t] = 0.f;
    for (int d = 0; d < 64; ++d) {
      float qd = Qs[qw][d];
      #pragma unroll
      for (int t = 0; t < 16; ++t) s[t] += qd * Ks[dg * 16 + t][d];
    }
    float p[16];
    float lmax = -1e30f;
    #pragma unroll
    for (int t = 0; t < 16; ++t) {
      int kg = k0 + dg * 16 + t;
      bool msk = (idrow[kg] == 0) && (kg != 0);
      float sv = msk ? -1e9f : s[t] * 0.125f;   // dh^-0.5 = 1/8; mask after scale
      p[t] = sv;
      lmax = fmaxf(lmax, sv);
    }
    float cmax = fmaxf(lmax, __shfl_xor(lmax, 16, 64));
    cmax = fmaxf(cmax, __shfl_xor(cmax, 32, 64));
    float m_new = fmaxf(m_run, cmax);
    float alpha = __expf(m_run - m_new);
    float lsum = 0.f;
    #pragma unroll
    for (int t = 0; t < 16; ++t) { p[t] = __expf(p[t] - m_new); lsum += p[t]; }
    lsum += __shfl_xor(lsum, 16, 64);
    lsum += __shfl_xor(lsum, 32, 64);
    l_run = l_run * alpha + lsum;
    m_run = m_new;
    #pragma unroll
    for (int t = 0; t < 16; ++t) O[t] *= alpha;
    // O[qw][dg*16+t2] += sum_j p_j * V[j][dg*16+t2]; p_j gathered via shfl
    #pragma unroll
    for (int g = 0; g < 4; ++g) {
      #pragma unroll
      for (int t = 0; t < 16; ++t) {
        float pj = __shfl(p[t], ql + 16 * g, 64);
        int j = g * 16 + t;
        #pragma unroll
        for (int t2 = 0; t2 < 16; ++t2) O[t2] += pj * Vs[j][dg * 16 + t2];
      }
    }
  }
  float inv = 1.f / l_run;
  unsigned short* op = Ob + ((long)(b * SEQ_L + q0 + qw)) * D_MODEL + h * 64 + dg * 16;
  #pragma unroll
  for (int t = 0; t < 16; ++t) op[t] = f2bf(O[t] * inv);
}

// ---------------- residual + LayerNorm (fp32), writes fp32 + bf16 ----------------
__global__ __launch_bounds__(256) void add_ln(
    const float* __restrict__ Xin, const float* __restrict__ Yin,
    const float* __restrict__ g, const float* __restrict__ bta,
    float* __restrict__ outF, unsigned short* __restrict__ outB,
    long in_stride, long out_stride) {
  int row = blockIdx.x;
  const float* x = Xin + (long)row * in_stride;
  const float* y = Yin ? Yin + (long)row * 1024 : nullptr;
  int tid = threadIdx.x;
  float v[4];
  float s = 0.f, s2 = 0.f;
  #pragma unroll
  for (int j = 0; j < 4; ++j) {
    int d = j * 256 + tid;
    float t = x[d] + (y ? y[d] : 0.f);
    v[j] = t; s += t; s2 += t * t;
  }
  __shared__ float red[8];
  int lane = tid & 63, wave = tid >> 6;
  #pragma unroll
  for (int o = 32; o > 0; o >>= 1) { s += __shfl_down(s, o, 64); s2 += __shfl_down(s2, o, 64); }
  if (lane == 0) { red[wave] = s; red[4 + wave] = s2; }
  __syncthreads();
  s  = red[0] + red[1] + red[2] + red[3];
  s2 = red[4] + red[5] + red[6] + red[7];
  float mean = s * (1.f / 1024.f);
  float var  = s2 * (1.f / 1024.f) - mean * mean;   // population var (ddof=0)
  float rstd = rsqrtf(var + 1e-5f);
  float* of = outF + (long)row * out_stride;
  unsigned short* ob = outB ? outB + (long)row * out_stride : nullptr;
  #pragma unroll
  for (int j = 0; j < 4; ++j) {
    int d = j * 256 + tid;
    float o = (v[j] - mean) * rstd * g[d] + bta[d];
    of[d] = o;
    if (ob) ob[d] = f2bf(o);
  }
}

// ---------------- head: out[b,n] = dot(cls_ln[b], head_W[n]) + head_b[n] ----------------
__global__ __launch_bounds__(256) void head_kernel(
    const float* __restrict__ cls, const float* __restrict__ hW,
    const float* __restrict__ hb, float* __restrict__ out) {
  int n = blockIdx.x * 256 + threadIdx.x;   // 0..1023
  int b = blockIdx.y;
  const float4* c4 = (const float4*)(cls + b * 1024);
  const float4* w4 = (const float4*)(hW + (long)n * 1024);
  float s = 0.f;
  #pragma unroll 8
  for (int d = 0; d < 256; ++d) {
    float4 a = c4[d], w = w4[d];
    s += a.x * w.x + a.y * w.y + a.z * w.z + a.w * w.w;
  }
  out[b * 1024 + n] = s + hb[n];
}

extern "C" void kernel_launch(void* const* d_in, const int* in_sizes, int n_in,
                              void* d_out, int out_size, void* d_ws, size_t ws_size,
                              hipStream_t stream) {
  const int*   ids  = (const int*)d_in[0];
  const float* tok  = (const float*)d_in[1];
  const float* pos  = (const float*)d_in[2];
  const float* Wqkv = (const float*)d_in[3];
  const float* bqkv = (const float*)d_in[4];
  const float* Wo   = (const float*)d_in[5];
  const float* bo   = (const float*)d_in[6];
  const float* ln1g = (const float*)d_in[7];
  const float* ln1b = (const float*)d_in[8];
  const float* W1   = (const float*)d_in[9];
  const float* b1   = (const float*)d_in[10];
  const float* W2   = (const float*)d_in[11];
  const float* b2   = (const float*)d_in[12];
  const float* ln2g = (const float*)d_in[13];
  const float* ln2b = (const float*)d_in[14];
  const float* hlng = (const float*)d_in[15];
  const float* hlnb = (const float*)d_in[16];
  const float* hW   = (const float*)d_in[17];
  const float* hb   = (const float*)d_in[18];
  float* out = (float*)d_out;

  char* ws = (char*)d_ws;
  size_t off = 0;
  auto alloc = [&](size_t bytes) {
    char* p = ws + off;
    off = (off + bytes + 255) & ~(size_t)255;
    return p;
  };
  unsigned short* Wqkv_b = (unsigned short*)alloc((size_t)NLAYER*3072*1024*2);
  unsigned short* Wo_b   = (unsigned short*)alloc((size_t)NLAYER*1024*1024*2);
  unsigned short* W1_b   = (unsigned short*)alloc((size_t)NLAYER*4096*1024*2);
  unsigned short* W2_b   = (unsigned short*)alloc((size_t)NLAYER*1024*4096*2);
  float*          X      = (float*)alloc((size_t)TOKENS*1024*4);
  unsigned short* Xb     = (unsigned short*)alloc((size_t)TOKENS*1024*2);
  float*          T1     = (float*)alloc((size_t)TOKENS*3072*4);   // qkv fp32
  float*          Y      = (float*)alloc((size_t)TOKENS*1024*4);
  unsigned short* Ab     = (unsigned short*)alloc((size_t)TOKENS*1024*2);
  unsigned short* Gb     = (unsigned short*)T1;  // FF intermediate aliases dead qkv (64MB<=96MB)
  float*          cls    = (float*)alloc(8*1024*4);

  f2b_kernel<<<2048, 256, 0, stream>>>(Wqkv, Wqkv_b, (long)NLAYER*3072*1024);
  f2b_kernel<<<2048, 256, 0, stream>>>(Wo,   Wo_b,   (long)NLAYER*1024*1024);
  f2b_kernel<<<2048, 256, 0, stream>>>(W1,   W1_b,   (long)NLAYER*4096*1024);
  f2b_kernel<<<2048, 256, 0, stream>>>(W2,   W2_b,   (long)NLAYER*1024*4096);
  embed_kernel<<<(TOKENS*1024)/256, 256, 0, stream>>>(ids, tok, pos, X, Xb);

  for (int i = 0; i < NLAYER; ++i) {
    gemm_bt<0><<<dim3(3072/64, TOKENS/16), 256, 0, stream>>>(
        Xb, Wqkv_b + (size_t)i*3072*1024, bqkv + i*3072, T1, nullptr, TOKENS, 3072, 1024);
    attn_kernel<<<dim3(SEQ_L/64, NHEAD, SEQ_B), 256, 0, stream>>>(T1, ids, Ab);
    gemm_bt<0><<<dim3(1024/64, TOKENS/16), 256, 0, stream>>>(
        Ab, Wo_b + (size_t)i*1024*1024, bo + i*1024, Y, nullptr, TOKENS, 1024, 1024);
    add_ln<<<TOKENS, 256, 0, stream>>>(X, Y, ln1g + i*1024, ln1b + i*1024, X, Xb, 1024L, 1024L);
    gemm_bt<1><<<dim3(4096/64, TOKENS/16), 256, 0, stream>>>(
        Xb, W1_b + (size_t)i*4096*1024, b1 + i*4096, nullptr, Gb, TOKENS, 4096, 1024);
    gemm_bt<0><<<dim3(1024/64, TOKENS/16), 256, 0, stream>>>(
        Gb, W2_b + (size_t)i*1024*4096, b2 + i*1024, Y, nullptr, TOKENS, 1024, 4096);
    add_ln<<<TOKENS, 256, 0, stream>>>(X, Y, ln2g + i*1024, ln2b + i*1024, X, Xb, 1024L, 1024L);
  }
  // head: LN over cls rows (stride L*D), then dense 1024x1024
  add_ln<<<8, 256, 0, stream>>>(X, nullptr, hlng, hlnb, cls, nullptr, (long)SEQ_L*1024, 1024L);
  head_kernel<<<dim3(4, 8), 256, 0, stream>>>(cls, hW, hb, out);
}

// Round 2
// 3406.820 us; speedup vs baseline: 9.9281x; 9.9281x over previous
//
#include <hip/hip_runtime.h>
#include <cstdint>

#define D_MODEL 1024
#define NHEAD   16
#define NLAYER  6
#define DIM_FF  4096
#define SEQ_B   8
#define SEQ_L   1024
#define TOKENS  (SEQ_B*SEQ_L)   // 8192

typedef __bf16 v8bf __attribute__((ext_vector_type(8)));
typedef float  v4f  __attribute__((ext_vector_type(4)));

__device__ __forceinline__ unsigned short f2bf(float f) {
  unsigned int u = __float_as_uint(f);
  u += 0x7fffu + ((u >> 16) & 1u);      // round-to-nearest-even
  return (unsigned short)(u >> 16);
}

__device__ __forceinline__ void gl_lds16(const void* g, void* l) {
  __builtin_amdgcn_global_load_lds(
      (const __attribute__((address_space(1))) void*)g,
      (__attribute__((address_space(3))) void*)l, 16, 0, 0);
}

// ---------------- weight fp32 -> bf16 ----------------
__global__ __launch_bounds__(256) void f2b_kernel(const float* __restrict__ in,
                                                  unsigned short* __restrict__ out, long n) {
  long i = (long)blockIdx.x * 256 + threadIdx.x;
  long stride = (long)gridDim.x * 256;
  for (; i < n; i += stride) out[i] = f2bf(in[i]);
}

// ---------------- embedding ----------------
__global__ __launch_bounds__(256) void embed_kernel(const int* __restrict__ ids,
    const float* __restrict__ tok, const float* __restrict__ pos,
    float* __restrict__ X, unsigned short* __restrict__ Xb) {
  long i = (long)blockIdx.x * 256 + threadIdx.x;   // over TOKENS*D_MODEL
  int d = (int)(i & (D_MODEL - 1));
  long bl = i >> 10;
  int l = (int)(bl & (SEQ_L - 1));
  int id = ids[bl];
  float v = tok[(long)id * D_MODEL + d] + pos[(long)l * D_MODEL + d];
  X[i] = v; Xb[i] = f2bf(v);
}

// ---------------- 128x128 GEMM: C[M,N] = A[M,K] @ W[N,K]^T + bias ----------------
// m97 structure: BK=32, global_load_lds width16, 4 waves (2x2 of 64x64), 4x4 mfma tiles.
// EPI: 0 = fp32 -> Cf; 1 = gelu -> bf16 Cb; 2 = bf16 -> Cb;
//      3 = QKV: cols<2048 bf16 -> Cb, cols>=2048 (V) transposed bf16 -> Vt[(b*16+h)*64+d][l]
template<int EPI>
__global__ __launch_bounds__(256) void gemm128(
    const unsigned short* __restrict__ A,
    const unsigned short* __restrict__ W,
    const float* __restrict__ bias,
    float* __restrict__ Cf, unsigned short* __restrict__ Cb,
    unsigned short* __restrict__ Vt,
    int M, int N, int K) {
  __shared__ unsigned short As[128 * 32];
  __shared__ unsigned short Bs[128 * 32];
  int tid = threadIdx.x;
  int wave = tid >> 6, lane = tid & 63;
  int l15 = lane & 15, quad = lane >> 4;
  int m0 = blockIdx.y * 128, n0 = blockIdx.x * 128;
  int wm = (wave >> 1) * 64, wn = (wave & 1) * 64;

  // staging: thread t covers flat f = t and t+256; f -> row f>>2, kcol (f&3)*8
  int srow = tid >> 2, sc8 = (tid & 3) << 3;
  const unsigned short* Ag0 = A + (long)(m0 + srow) * K + sc8;
  const unsigned short* Ag1 = A + (long)(m0 + srow + 64) * K + sc8;
  const unsigned short* Wg0 = W + (long)(n0 + srow) * K + sc8;
  const unsigned short* Wg1 = W + (long)(n0 + srow + 64) * K + sc8;
  unsigned short* As0 = As + tid * 8;
  unsigned short* As1 = As + tid * 8 + 2048;
  unsigned short* Bs0 = Bs + tid * 8;
  unsigned short* Bs1 = Bs + tid * 8 + 2048;

  v4f acc[4][4];
  #pragma unroll
  for (int i = 0; i < 4; ++i)
    #pragma unroll
    for (int j = 0; j < 4; ++j) acc[i][j] = (v4f){0.f, 0.f, 0.f, 0.f};

  int ksteps = K >> 5;
  for (int ks = 0; ks < ksteps; ++ks) {
    int k0 = ks << 5;
    __syncthreads();
    gl_lds16(Ag0 + k0, As0);
    gl_lds16(Ag1 + k0, As1);
    gl_lds16(Wg0 + k0, Bs0);
    gl_lds16(Wg1 + k0, Bs1);
    __syncthreads();   // drains vmcnt -> LDS tiles ready
    v8bf af[4], bf[4];
    #pragma unroll
    for (int i = 0; i < 4; ++i)
      af[i] = *(const v8bf*)&As[(wm + i * 16 + l15) * 32 + quad * 8];
    #pragma unroll
    for (int j = 0; j < 4; ++j)
      bf[j] = *(const v8bf*)&Bs[(wn + j * 16 + l15) * 32 + quad * 8];
    #pragma unroll
    for (int i = 0; i < 4; ++i)
      #pragma unroll
      for (int j = 0; j < 4; ++j)
        acc[i][j] = __builtin_amdgcn_mfma_f32_16x16x32_bf16(af[i], bf[j], acc[i][j], 0, 0, 0);
  }

  #pragma unroll
  for (int i = 0; i < 4; ++i) {
    int crow0 = m0 + wm + i * 16 + quad * 4;
    #pragma unroll
    for (int j = 0; j < 4; ++j) {
      int col = n0 + wn + j * 16 + l15;
      float bv = bias[col];
      if (EPI == 3 && col >= 2048) {
        // V head: write transposed. 4 consecutive rows -> 4 consecutive l.
        int hc = (col - 2048) >> 6, d = (col - 2048) & 63;
        int bb = crow0 >> 10, l = crow0 & 1023;
        ushort4 pk;
        pk.x = f2bf(acc[i][j][0] + bv);
        pk.y = f2bf(acc[i][j][1] + bv);
        pk.z = f2bf(acc[i][j][2] + bv);
        pk.w = f2bf(acc[i][j][3] + bv);
        *(ushort4*)&Vt[((long)((bb * 16 + hc) * 64 + d)) * 1024 + l] = pk;
      } else {
        #pragma unroll
        for (int r = 0; r < 4; ++r) {
          float v = acc[i][j][r] + bv;
          if (EPI == 1) v = 0.5f * v * (1.f + erff(v * 0.70710678118f));
          long idx = (long)(crow0 + r) * N + col;
          if (EPI == 0) Cf[idx] = v;
          else          Cb[idx] = f2bf(v);
        }
      }
    }
  }
}

// ---------------- MFMA flash attention ----------------
// grid (L/64, NHEAD, B), block 256 (4 waves; wave w owns q rows q0+w*16..+16).
// QKVb: (8192, 3072) bf16 q|k|(v unused). Vtg: (B*H*64 d-rows, 1024 l) bf16.
#define KP 72   // padded LDS row stride (elems); 144B = 16B-aligned
__global__ __launch_bounds__(256) void attn2(
    const unsigned short* __restrict__ QKVb,
    const unsigned short* __restrict__ Vtg,
    const int* __restrict__ ids,
    unsigned short* __restrict__ Ob) {
  __shared__ unsigned short Ks[64 * KP];     // [key][d]
  __shared__ unsigned short Vs[64 * KP];     // [d][key]  (from pre-transposed Vt)
  __shared__ unsigned short Ps[4][16 * KP];  // per-wave P [q][key]
  int tid = threadIdx.x, wave = tid >> 6, lane = tid & 63;
  int l15 = lane & 15, quad = lane >> 4;
  int b = blockIdx.z, h = blockIdx.y, q0 = blockIdx.x * 64;

  // Q fragments (registers, loaded once)
  int qrow = q0 + wave * 16 + l15;
  const unsigned short* qb = QKVb + (long)(b * 1024 + qrow) * 3072 + h * 64;
  v8bf gq0 = *(const v8bf*)(qb + quad * 8);
  v8bf gq1 = *(const v8bf*)(qb + 32 + quad * 8);

  float m_run[4], l_run[4];
  v4f O[4];
  #pragma unroll
  for (int r = 0; r < 4; ++r) { m_run[r] = -1e30f; l_run[r] = 0.f; }
  #pragma unroll
  for (int j = 0; j < 4; ++j) O[j] = (v4f){0.f, 0.f, 0.f, 0.f};

  const unsigned short* kgb = QKVb + (long)b * 1024 * 3072 + 1024 + h * 64;
  const unsigned short* vgb = Vtg + (long)((b * 16 + h) * 64) * 1024;
  const int* idrow = ids + b * 1024;

  for (int k0 = 0; k0 < SEQ_L; k0 += 64) {
    __syncthreads();
    #pragma unroll
    for (int it = 0; it < 2; ++it) {
      int f = it * 256 + tid;
      int row = f >> 3, e8 = (f & 7) << 3;
      v8bf kv = *(const v8bf*)(kgb + (long)(k0 + row) * 3072 + e8);
      *(v8bf*)&Ks[row * KP + e8] = kv;
      v8bf vv = *(const v8bf*)(vgb + (long)row * 1024 + k0 + e8);
      *(v8bf*)&Vs[row * KP + e8] = vv;
    }
    __syncthreads();

    // scores: 4 tiles of 16 keys; D rows=q (quad*4+r), cols=key (l15)
    float p[4][4], mr[4];
    #pragma unroll
    for (int r = 0; r < 4; ++r) mr[r] = -1e30f;
    #pragma unroll
    for (int t = 0; t < 4; ++t) {
      v8bf kf0 = *(const v8bf*)&Ks[(t * 16 + l15) * KP + quad * 8];
      v8bf kf1 = *(const v8bf*)&Ks[(t * 16 + l15) * KP + 32 + quad * 8];
      v4f s = (v4f){0.f, 0.f, 0.f, 0.f};
      s = __builtin_amdgcn_mfma_f32_16x16x32_bf16(gq0, kf0, s, 0, 0, 0);
      s = __builtin_amdgcn_mfma_f32_16x16x32_bf16(gq1, kf1, s, 0, 0, 0);
      int kg = k0 + t * 16 + l15;
      bool msk = (idrow[kg] == 0) && (kg != 0);
      #pragma unroll
      for (int r = 0; r < 4; ++r) {
        float sv = msk ? -1e9f : s[r] * 0.125f;
        p[t][r] = sv;
        mr[r] = fmaxf(mr[r], sv);
      }
    }
    #pragma unroll
    for (int r = 0; r < 4; ++r) {
      mr[r] = fmaxf(mr[r], __shfl_xor(mr[r], 1, 64));
      mr[r] = fmaxf(mr[r], __shfl_xor(mr[r], 2, 64));
      mr[r] = fmaxf(mr[r], __shfl_xor(mr[r], 4, 64));
      mr[r] = fmaxf(mr[r], __shfl_xor(mr[r], 8, 64));
    }
    float alpha[4], ls[4];
    #pragma unroll
    for (int r = 0; r < 4; ++r) {
      float mn = fmaxf(m_run[r], mr[r]);
      alpha[r] = __expf(m_run[r] - mn);
      m_run[r] = mn; ls[r] = 0.f;
    }
    #pragma unroll
    for (int t = 0; t < 4; ++t)
      #pragma unroll
      for (int r = 0; r < 4; ++r) {
        p[t][r] = __expf(p[t][r] - m_run[r]);
        ls[r] += p[t][r];
      }
    #pragma unroll
    for (int r = 0; r < 4; ++r) {
      ls[r] += __shfl_xor(ls[r], 1, 64);
      ls[r] += __shfl_xor(ls[r], 2, 64);
      ls[r] += __shfl_xor(ls[r], 4, 64);
      ls[r] += __shfl_xor(ls[r], 8, 64);
      l_run[r] = l_run[r] * alpha[r] + ls[r];
    }
    #pragma unroll
    for (int j = 0; j < 4; ++j)
      #pragma unroll
      for (int r = 0; r < 4; ++r) O[j][r] *= alpha[r];

    // P: C-layout -> LDS -> A-layout (wave-local; in-order LDS ops, no barrier)
    #pragma unroll
    for (int t = 0; t < 4; ++t)
      #pragma unroll
      for (int r = 0; r < 4; ++r)
        Ps[wave][(quad * 4 + r) * KP + t * 16 + l15] = f2bf(p[t][r]);
    v8bf pa0 = *(const v8bf*)&Ps[wave][l15 * KP + quad * 8];
    v8bf pa1 = *(const v8bf*)&Ps[wave][l15 * KP + 32 + quad * 8];
    #pragma unroll
    for (int j = 0; j < 4; ++j) {
      v8bf vf0 = *(const v8bf*)&Vs[(j * 16 + l15) * KP + quad * 8];
      v8bf vf1 = *(const v8bf*)&Vs[(j * 16 + l15) * KP + 32 + quad * 8];
      O[j] = __builtin_amdgcn_mfma_f32_16x16x32_bf16(pa0, vf0, O[j], 0, 0, 0);
      O[j] = __builtin_amdgcn_mfma_f32_16x16x32_bf16(pa1, vf1, O[j], 0, 0, 0);
    }
  }

  int qd = q0 + wave * 16 + quad * 4;
  #pragma unroll
  for (int r = 0; r < 4; ++r) {
    float inv = 1.f / l_run[r];
    #pragma unroll
    for (int j = 0; j < 4; ++j)
      Ob[(long)(b * 1024 + qd + r) * 1024 + h * 64 + j * 16 + l15] = f2bf(O[j][r] * inv);
  }
}

// ---------------- residual + LayerNorm (fp32), writes fp32 + bf16 ----------------
__global__ __launch_bounds__(256) void add_ln(
    const float* __restrict__ Xin, const float* __restrict__ Yin,
    const float* __restrict__ g, const float* __restrict__ bta,
    float* __restrict__ outF, unsigned short* __restrict__ outB,
    long in_stride, long out_stride) {
  int row = blockIdx.x;
  const float* x = Xin + (long)row * in_stride;
  const float* y = Yin ? Yin + (long)row * 1024 : nullptr;
  int tid = threadIdx.x;
  float v[4];
  float s = 0.f, s2 = 0.f;
  #pragma unroll
  for (int j = 0; j < 4; ++j) {
    int d = j * 256 + tid;
    float t = x[d] + (y ? y[d] : 0.f);
    v[j] = t; s += t; s2 += t * t;
  }
  __shared__ float red[8];
  int lane = tid & 63, wave = tid >> 6;
  #pragma unroll
  for (int o = 32; o > 0; o >>= 1) { s += __shfl_down(s, o, 64); s2 += __shfl_down(s2, o, 64); }
  if (lane == 0) { red[wave] = s; red[4 + wave] = s2; }
  __syncthreads();
  s  = red[0] + red[1] + red[2] + red[3];
  s2 = red[4] + red[5] + red[6] + red[7];
  float mean = s * (1.f / 1024.f);
  float var  = s2 * (1.f / 1024.f) - mean * mean;   // population var (ddof=0)
  float rstd = rsqrtf(var + 1e-5f);
  float* of = outF + (long)row * out_stride;
  unsigned short* ob = outB ? outB + (long)row * out_stride : nullptr;
  #pragma unroll
  for (int j = 0; j < 4; ++j) {
    int d = j * 256 + tid;
    float o = (v[j] - mean) * rstd * g[d] + bta[d];
    of[d] = o;
    if (ob) ob[d] = f2bf(o);
  }
}

// ---------------- head ----------------
__global__ __launch_bounds__(256) void head_kernel(
    const float* __restrict__ cls, const float* __restrict__ hW,
    const float* __restrict__ hb, float* __restrict__ out) {
  int n = blockIdx.x * 256 + threadIdx.x;
  int b = blockIdx.y;
  const float4* c4 = (const float4*)(cls + b * 1024);
  const float4* w4 = (const float4*)(hW + (long)n * 1024);
  float s = 0.f;
  #pragma unroll 8
  for (int d = 0; d < 256; ++d) {
    float4 a = c4[d], w = w4[d];
    s += a.x * w.x + a.y * w.y + a.z * w.z + a.w * w.w;
  }
  out[b * 1024 + n] = s + hb[n];
}

extern "C" void kernel_launch(void* const* d_in, const int* in_sizes, int n_in,
                              void* d_out, int out_size, void* d_ws, size_t ws_size,
                              hipStream_t stream) {
  const int*   ids  = (const int*)d_in[0];
  const float* tok  = (const float*)d_in[1];
  const float* pos  = (const float*)d_in[2];
  const float* Wqkv = (const float*)d_in[3];
  const float* bqkv = (const float*)d_in[4];
  const float* Wo   = (const float*)d_in[5];
  const float* bo   = (const float*)d_in[6];
  const float* ln1g = (const float*)d_in[7];
  const float* ln1b = (const float*)d_in[8];
  const float* W1   = (const float*)d_in[9];
  const float* b1   = (const float*)d_in[10];
  const float* W2   = (const float*)d_in[11];
  const float* b2   = (const float*)d_in[12];
  const float* ln2g = (const float*)d_in[13];
  const float* ln2b = (const float*)d_in[14];
  const float* hlng = (const float*)d_in[15];
  const float* hlnb = (const float*)d_in[16];
  const float* hW   = (const float*)d_in[17];
  const float* hb   = (const float*)d_in[18];
  float* out = (float*)d_out;

  char* ws = (char*)d_ws;
  size_t off = 0;
  auto alloc = [&](size_t bytes) {
    char* p = ws + off;
    off = (off + bytes + 255) & ~(size_t)255;
    return p;
  };
  unsigned short* Wqkv_b = (unsigned short*)alloc((size_t)NLAYER*3072*1024*2);
  unsigned short* Wo_b   = (unsigned short*)alloc((size_t)NLAYER*1024*1024*2);
  unsigned short* W1_b   = (unsigned short*)alloc((size_t)NLAYER*4096*1024*2);
  unsigned short* W2_b   = (unsigned short*)alloc((size_t)NLAYER*1024*4096*2);
  float*          X      = (float*)alloc((size_t)TOKENS*1024*4);
  unsigned short* Xb     = (unsigned short*)alloc((size_t)TOKENS*1024*2);
  unsigned short* Qb     = (unsigned short*)alloc((size_t)TOKENS*3072*2);  // qkv bf16
  unsigned short* Vtg    = (unsigned short*)alloc((size_t)TOKENS*1024*2);  // V transposed
  float*          Y      = (float*)alloc((size_t)TOKENS*1024*4);
  unsigned short* Ab     = (unsigned short*)alloc((size_t)TOKENS*1024*2);
  unsigned short* Gb     = Qb;  // FF intermediate (67.1MB) aliases Qb+Vtg (50.3+16.8MB), both dead
  float*          cls    = (float*)alloc(8*1024*4);

  f2b_kernel<<<2048, 256, 0, stream>>>(Wqkv, Wqkv_b, (long)NLAYER*3072*1024);
  f2b_kernel<<<2048, 256, 0, stream>>>(Wo,   Wo_b,   (long)NLAYER*1024*1024);
  f2b_kernel<<<2048, 256, 0, stream>>>(W1,   W1_b,   (long)NLAYER*4096*1024);
  f2b_kernel<<<2048, 256, 0, stream>>>(W2,   W2_b,   (long)NLAYER*1024*4096);
  embed_kernel<<<(TOKENS*1024)/256, 256, 0, stream>>>(ids, tok, pos, X, Xb);

  for (int i = 0; i < NLAYER; ++i) {
    gemm128<3><<<dim3(3072/128, TOKENS/128), 256, 0, stream>>>(
        Xb, Wqkv_b + (size_t)i*3072*1024, bqkv + i*3072, nullptr, Qb, Vtg, TOKENS, 3072, 1024);
    attn2<<<dim3(SEQ_L/64, NHEAD, SEQ_B), 256, 0, stream>>>(Qb, Vtg, ids, Ab);
    gemm128<0><<<dim3(1024/128, TOKENS/128), 256, 0, stream>>>(
        Ab, Wo_b + (size_t)i*1024*1024, bo + i*1024, Y, nullptr, nullptr, TOKENS, 1024, 1024);
    add_ln<<<TOKENS, 256, 0, stream>>>(X, Y, ln1g + i*1024, ln1b + i*1024, X, Xb, 1024L, 1024L);
    gemm128<1><<<dim3(4096/128, TOKENS/128), 256, 0, stream>>>(
        Xb, W1_b + (size_t)i*4096*1024, b1 + i*4096, nullptr, Gb, nullptr, TOKENS, 4096, 1024);
    gemm128<0><<<dim3(1024/128, TOKENS/128), 256, 0, stream>>>(
        Gb, W2_b + (size_t)i*1024*4096, b2 + i*1024, Y, nullptr, nullptr, TOKENS, 1024, 4096);
    add_ln<<<TOKENS, 256, 0, stream>>>(X, Y, ln2g + i*1024, ln2b + i*1024, X, Xb, 1024L, 1024L);
  }
  add_ln<<<8, 256, 0, stream>>>(X, nullptr, hlng, hlnb, cls, nullptr, (long)SEQ_L*1024, 1024L);
  head_kernel<<<dim3(4, 8), 256, 0, stream>>>(cls, hW, hb, out);
}

// Round 3
// 3351.403 us; speedup vs baseline: 10.0923x; 1.0165x over previous
//
#include <hip/hip_runtime.h>
#include <cstdint>

#define D_MODEL 1024
#define NHEAD   16
#define NLAYER  6
#define DIM_FF  4096
#define SEQ_B   8
#define SEQ_L   1024
#define TOKENS  (SEQ_B*SEQ_L)   // 8192

typedef __bf16 v8bf  __attribute__((ext_vector_type(8)));
typedef __bf16 v4bf  __attribute__((ext_vector_type(4)));
typedef float  v4f   __attribute__((ext_vector_type(4)));

__device__ __forceinline__ void gl_lds16(const void* g, void* l) {
  __builtin_amdgcn_global_load_lds(
      (const __attribute__((address_space(1))) void*)g,
      (__attribute__((address_space(3))) void*)l, 16, 0, 0);
}

// ---------------- weight fp32 -> bf16 (vectorized) ----------------
__global__ __launch_bounds__(256) void f2b_kernel(const float4* __restrict__ in,
                                                  ushort4* __restrict__ out, long n4) {
  long i = (long)blockIdx.x * 256 + threadIdx.x;
  long stride = (long)gridDim.x * 256;
  for (; i < n4; i += stride) {
    float4 v = in[i];
    v4bf r = { (__bf16)v.x, (__bf16)v.y, (__bf16)v.z, (__bf16)v.w };
    out[i] = *(ushort4*)&r;
  }
}

// ---------------- embedding (vectorized) ----------------
__global__ __launch_bounds__(256) void embed_kernel(const int* __restrict__ ids,
    const float4* __restrict__ tok, const float4* __restrict__ pos,
    float4* __restrict__ X, ushort4* __restrict__ Xb) {
  long i = (long)blockIdx.x * 256 + threadIdx.x;   // over TOKENS*256
  int d4 = (int)(i & 255);
  long bl = i >> 8;
  int l = (int)(bl & (SEQ_L - 1));
  int id = ids[bl];
  float4 t = tok[(long)id * 256 + d4];
  float4 p = pos[(long)l * 256 + d4];
  float4 v = {t.x + p.x, t.y + p.y, t.z + p.z, t.w + p.w};
  X[i] = v;
  v4bf r = { (__bf16)v.x, (__bf16)v.y, (__bf16)v.z, (__bf16)v.w };
  Xb[i] = *(ushort4*)&r;
}

// ---------------- additive mask bias ----------------
__global__ __launch_bounds__(256) void maskb_kernel(const int* __restrict__ ids,
                                                    float* __restrict__ mb) {
  int i = blockIdx.x * 256 + threadIdx.x;   // 0..8191
  mb[i] = (ids[i] == 0 && (i & 1023) != 0) ? -1e9f : 0.f;
}

// ---------------- 128x128 GEMM: C[M,N] = A[M,K] @ W[N,K]^T + bias ----------------
// m97 structure + XOR-swizzled LDS (2-way free) + XCD-contiguous block mapping.
// EPI: 0 = fp32 -> Cf; 1 = gelu -> bf16 Cb;
//      3 = QKV: cols<2048 bf16 -> Cb, cols>=2048 (V) transposed -> Vt[(b*16+h)*64+d][l]
template<int EPI>
__global__ __launch_bounds__(256) void gemm128(
    const unsigned short* __restrict__ A,
    const unsigned short* __restrict__ W,
    const float* __restrict__ bias,
    float* __restrict__ Cf, unsigned short* __restrict__ Cb,
    unsigned short* __restrict__ Vt,
    int M, int N, int K) {
  __shared__ unsigned short As[128 * 32];
  __shared__ unsigned short Bs[128 * 32];
  int tid = threadIdx.x;
  int wave = tid >> 6, lane = tid & 63;
  int l15 = lane & 15, quad = lane >> 4;

  // XCD-contiguous supertile: 8 M-tiles per XCD, N slow (gridDim.y == 64 always here)
  int id = blockIdx.y * gridDim.x + blockIdx.x;
  int xcd = id & 7, sidx = id >> 3;
  int mt = xcd * 8 + (sidx & 7);
  int nt = sidx >> 3;
  int m0 = mt * 128, n0 = nt * 128;
  int wm = (wave >> 1) * 64, wn = (wave & 1) * 64;

  // staging: thread t -> LDS unit t (row t>>2, phys slot t&3); global slot XOR-swizzled
  int srow = tid >> 2;
  int ssl  = (tid & 3) ^ ((srow >> 1) & 3);
  int sc8  = ssl << 3;
  const unsigned short* Ag0 = A + (long)(m0 + srow) * K + sc8;
  const unsigned short* Ag1 = A + (long)(m0 + srow + 64) * K + sc8;
  const unsigned short* Wg0 = W + (long)(n0 + srow) * K + sc8;
  const unsigned short* Wg1 = W + (long)(n0 + srow + 64) * K + sc8;
  unsigned short* As0 = As + tid * 8;
  unsigned short* As1 = As + tid * 8 + 2048;
  unsigned short* Bs0 = Bs + tid * 8;
  unsigned short* Bs1 = Bs + tid * 8 + 2048;

  // fragment read pointers (hoisted; swizzle-inverted)
  const unsigned short* afp[4];
  const unsigned short* bfp[4];
  #pragma unroll
  for (int i = 0; i < 4; ++i) {
    int r = wm + i * 16 + l15;
    afp[i] = &As[r * 32 + ((quad ^ ((r >> 1) & 3)) << 3)];
    int rb = wn + i * 16 + l15;
    bfp[i] = &Bs[rb * 32 + ((quad ^ ((rb >> 1) & 3)) << 3)];
  }

  v4f acc[4][4];
  #pragma unroll
  for (int i = 0; i < 4; ++i)
    #pragma unroll
    for (int j = 0; j < 4; ++j) acc[i][j] = (v4f){0.f, 0.f, 0.f, 0.f};

  int ksteps = K >> 5;
  for (int ks = 0; ks < ksteps; ++ks) {
    int k0 = ks << 5;
    __syncthreads();
    gl_lds16(Ag0 + k0, As0);
    gl_lds16(Ag1 + k0, As1);
    gl_lds16(Wg0 + k0, Bs0);
    gl_lds16(Wg1 + k0, Bs1);
    __syncthreads();
    v8bf af[4], bf[4];
    #pragma unroll
    for (int i = 0; i < 4; ++i) af[i] = *(const v8bf*)afp[i];
    #pragma unroll
    for (int j = 0; j < 4; ++j) bf[j] = *(const v8bf*)bfp[j];
    #pragma unroll
    for (int i = 0; i < 4; ++i)
      #pragma unroll
      for (int j = 0; j < 4; ++j)
        acc[i][j] = __builtin_amdgcn_mfma_f32_16x16x32_bf16(af[i], bf[j], acc[i][j], 0, 0, 0);
  }

  #pragma unroll
  for (int i = 0; i < 4; ++i) {
    int crow0 = m0 + wm + i * 16 + quad * 4;
    #pragma unroll
    for (int j = 0; j < 4; ++j) {
      int col = n0 + wn + j * 16 + l15;
      float bv = bias[col];
      if (EPI == 3 && col >= 2048) {
        int hc = (col - 2048) >> 6, d = (col - 2048) & 63;
        int bb = crow0 >> 10, l = crow0 & 1023;
        v4bf pk = { (__bf16)(acc[i][j][0] + bv), (__bf16)(acc[i][j][1] + bv),
                    (__bf16)(acc[i][j][2] + bv), (__bf16)(acc[i][j][3] + bv) };
        *(ushort4*)&Vt[((long)((bb * 16 + hc) * 64 + d)) * 1024 + l] = *(ushort4*)&pk;
      } else {
        #pragma unroll
        for (int r = 0; r < 4; ++r) {
          float v = acc[i][j][r] + bv;
          if (EPI == 1) v = 0.5f * v * (1.f + erff(v * 0.70710678118f));
          long idx = (long)(crow0 + r) * N + col;
          if (EPI == 0) Cf[idx] = v;
          else          ((__bf16*)Cb)[idx] = (__bf16)v;
        }
      }
    }
  }
}

// ---------------- MFMA flash attention ----------------
// grid (L/64, NHEAD, B), block 256. K/V staged via global_load_lds with XOR-swizzle.
#define PSP 72
__global__ __launch_bounds__(256) void attn2(
    const unsigned short* __restrict__ QKVb,
    const unsigned short* __restrict__ Vtg,
    const float* __restrict__ mb,
    unsigned short* __restrict__ Ob) {
  __shared__ unsigned short Ks[64 * 64];     // [key][d]  (swizzled slots)
  __shared__ unsigned short Vs[64 * 64];     // [d][key]
  __shared__ unsigned short Ps[4][16 * PSP]; // per-wave P [q][key], padded
  int tid = threadIdx.x, wave = tid >> 6, lane = tid & 63;
  int l15 = lane & 15, quad = lane >> 4;
  int b = blockIdx.z, h = blockIdx.y, q0 = blockIdx.x * 64;

  int qrow = q0 + wave * 16 + l15;
  const unsigned short* qb = QKVb + (long)(b * 1024 + qrow) * 3072 + h * 64;
  v8bf gq0 = *(const v8bf*)(qb + quad * 8);
  v8bf gq1 = *(const v8bf*)(qb + 32 + quad * 8);

  v8bf bones;   // B-frag with ones in column 0 -> row-sum MFMA
  #pragma unroll
  for (int j = 0; j < 8; ++j) bones[j] = (l15 == 0) ? (__bf16)1.0f : (__bf16)0.0f;

  float m_run[4], l_run[4];
  v4f O[4];
  #pragma unroll
  for (int r = 0; r < 4; ++r) { m_run[r] = -1e30f; l_run[r] = 0.f; }
  #pragma unroll
  for (int j = 0; j < 4; ++j) O[j] = (v4f){0.f, 0.f, 0.f, 0.f};

  const unsigned short* kgb = QKVb + (long)b * 1024 * 3072 + 1024 + h * 64;
  const unsigned short* vgb = Vtg + (long)((b * 16 + h) * 64) * 1024;
  const float* mrow = mb + b * 1024;

  // staging geometry: unit u = tid / tid+256 -> row u>>3, phys slot u&7
  int srow = tid >> 3;                  // 0..31
  int ssl  = (tid & 7) ^ (srow & 7);    // swizzled global slot (rows+32: same, 32%8==0)
  int ph0 = (quad ^ (l15 & 7)) << 3;          // phys offset for logical slot quad
  int ph1 = ((quad + 4) ^ (l15 & 7)) << 3;    // for logical slot quad+4
  const float SC = 0.18033688011112042f;      // 0.125 * log2(e)

  for (int k0 = 0; k0 < SEQ_L; k0 += 64) {
    __syncthreads();
    gl_lds16(kgb + (long)(k0 + srow) * 3072 + ssl * 8, &Ks[tid * 8]);
    gl_lds16(kgb + (long)(k0 + srow + 32) * 3072 + ssl * 8, &Ks[tid * 8 + 2048]);
    gl_lds16(vgb + (long)srow * 1024 + k0 + ssl * 8, &Vs[tid * 8]);
    gl_lds16(vgb + (long)(srow + 32) * 1024 + k0 + ssl * 8, &Vs[tid * 8 + 2048]);
    __syncthreads();

    float p[4][4], mr[4];
    #pragma unroll
    for (int r = 0; r < 4; ++r) mr[r] = -1e30f;
    #pragma unroll
    for (int t = 0; t < 4; ++t) {
      int kr = t * 16 + l15;
      v8bf kf0 = *(const v8bf*)&Ks[kr * 64 + ph0];
      v8bf kf1 = *(const v8bf*)&Ks[kr * 64 + ph1];
      v4f s = (v4f){0.f, 0.f, 0.f, 0.f};
      s = __builtin_amdgcn_mfma_f32_16x16x32_bf16(gq0, kf0, s, 0, 0, 0);
      s = __builtin_amdgcn_mfma_f32_16x16x32_bf16(gq1, kf1, s, 0, 0, 0);
      float bv = mrow[k0 + kr];
      #pragma unroll
      for (int r = 0; r < 4; ++r) {
        float sv = fmaf(s[r], SC, bv);   // exp2 domain; bias = 0 or -1e9
        p[t][r] = sv;
        mr[r] = fmaxf(mr[r], sv);
      }
    }
    #pragma unroll
    for (int r = 0; r < 4; ++r) {
      mr[r] = fmaxf(mr[r], __shfl_xor(mr[r], 1, 64));
      mr[r] = fmaxf(mr[r], __shfl_xor(mr[r], 2, 64));
      mr[r] = fmaxf(mr[r], __shfl_xor(mr[r], 4, 64));
      mr[r] = fmaxf(mr[r], __shfl_xor(mr[r], 8, 64));
    }
    float alpha[4];
    #pragma unroll
    for (int r = 0; r < 4; ++r) {
      float mn = fmaxf(m_run[r], mr[r]);
      alpha[r] = __builtin_amdgcn_exp2f(m_run[r] - mn);
      m_run[r] = mn;
    }
    #pragma unroll
    for (int t = 0; t < 4; ++t)
      #pragma unroll
      for (int r = 0; r < 4; ++r)
        p[t][r] = __builtin_amdgcn_exp2f(p[t][r] - m_run[r]);

    // P: C-layout -> LDS -> A-layout (wave-local, in-order LDS)
    #pragma unroll
    for (int t = 0; t < 4; ++t)
      #pragma unroll
      for (int r = 0; r < 4; ++r)
        ((__bf16*)Ps[wave])[(quad * 4 + r) * PSP + t * 16 + l15] = (__bf16)p[t][r];
    v8bf pa0 = *(const v8bf*)&Ps[wave][l15 * PSP + quad * 8];
    v8bf pa1 = *(const v8bf*)&Ps[wave][l15 * PSP + 32 + quad * 8];

    // row sums via ones-MFMA (col 0 of C holds sum over 64 keys)
    v4f ss = (v4f){0.f, 0.f, 0.f, 0.f};
    ss = __builtin_amdgcn_mfma_f32_16x16x32_bf16(pa0, bones, ss, 0, 0, 0);
    ss = __builtin_amdgcn_mfma_f32_16x16x32_bf16(pa1, bones, ss, 0, 0, 0);

    #pragma unroll
    for (int j = 0; j < 4; ++j)
      #pragma unroll
      for (int r = 0; r < 4; ++r) O[j][r] *= alpha[r];
    #pragma unroll
    for (int j = 0; j < 4; ++j) {
      v8bf vf0 = *(const v8bf*)&Vs[(j * 16 + l15) * 64 + ph0];
      v8bf vf1 = *(const v8bf*)&Vs[(j * 16 + l15) * 64 + ph1];
      O[j] = __builtin_amdgcn_mfma_f32_16x16x32_bf16(pa0, vf0, O[j], 0, 0, 0);
      O[j] = __builtin_amdgcn_mfma_f32_16x16x32_bf16(pa1, vf1, O[j], 0, 0, 0);
    }
    #pragma unroll
    for (int r = 0; r < 4; ++r)
      l_run[r] = l_run[r] * alpha[r] + __shfl(ss[r], quad << 4, 64);
  }

  int qd = q0 + wave * 16 + quad * 4;
  #pragma unroll
  for (int r = 0; r < 4; ++r) {
    float inv = 1.f / l_run[r];
    #pragma unroll
    for (int j = 0; j < 4; ++j)
      ((__bf16*)Ob)[(long)(b * 1024 + qd + r) * 1024 + h * 64 + j * 16 + l15] =
          (__bf16)(O[j][r] * inv);
  }
}

// ---------------- residual + LayerNorm (fp32), writes fp32 + bf16 ----------------
__global__ __launch_bounds__(256) void add_ln(
    const float* __restrict__ Xin, const float* __restrict__ Yin,
    const float* __restrict__ g, const float* __restrict__ bta,
    float* __restrict__ outF, unsigned short* __restrict__ outB,
    long in_stride, long out_stride) {
  int row = blockIdx.x;
  const float* x = Xin + (long)row * in_stride;
  const float* y = Yin ? Yin + (long)row * 1024 : nullptr;
  int tid = threadIdx.x;
  float v[4];
  float s = 0.f, s2 = 0.f;
  #pragma unroll
  for (int j = 0; j < 4; ++j) {
    int d = j * 256 + tid;
    float t = x[d] + (y ? y[d] : 0.f);
    v[j] = t; s += t; s2 += t * t;
  }
  __shared__ float red[8];
  int lane = tid & 63, wave = tid >> 6;
  #pragma unroll
  for (int o = 32; o > 0; o >>= 1) { s += __shfl_down(s, o, 64); s2 += __shfl_down(s2, o, 64); }
  if (lane == 0) { red[wave] = s; red[4 + wave] = s2; }
  __syncthreads();
  s  = red[0] + red[1] + red[2] + red[3];
  s2 = red[4] + red[5] + red[6] + red[7];
  float mean = s * (1.f / 1024.f);
  float var  = s2 * (1.f / 1024.f) - mean * mean;
  float rstd = rsqrtf(var + 1e-5f);
  float* of = outF + (long)row * out_stride;
  unsigned short* ob = outB ? outB + (long)row * out_stride : nullptr;
  #pragma unroll
  for (int j = 0; j < 4; ++j) {
    int d = j * 256 + tid;
    float o = (v[j] - mean) * rstd * g[d] + bta[d];
    of[d] = o;
    if (ob) ((__bf16*)ob)[d] = (__bf16)o;
  }
}

// ---------------- head ----------------
__global__ __launch_bounds__(256) void head_kernel(
    const float* __restrict__ cls, const float* __restrict__ hW,
    const float* __restrict__ hb, float* __restrict__ out) {
  int n = blockIdx.x * 256 + threadIdx.x;
  int b = blockIdx.y;
  const float4* c4 = (const float4*)(cls + b * 1024);
  const float4* w4 = (const float4*)(hW + (long)n * 1024);
  float s = 0.f;
  #pragma unroll 8
  for (int d = 0; d < 256; ++d) {
    float4 a = c4[d], w = w4[d];
    s += a.x * w.x + a.y * w.y + a.z * w.z + a.w * w.w;
  }
  out[b * 1024 + n] = s + hb[n];
}

extern "C" void kernel_launch(void* const* d_in, const int* in_sizes, int n_in,
                              void* d_out, int out_size, void* d_ws, size_t ws_size,
                              hipStream_t stream) {
  const int*   ids  = (const int*)d_in[0];
  const float* tok  = (const float*)d_in[1];
  const float* pos  = (const float*)d_in[2];
  const float* Wqkv = (const float*)d_in[3];
  const float* bqkv = (const float*)d_in[4];
  const float* Wo   = (const float*)d_in[5];
  const float* bo   = (const float*)d_in[6];
  const float* ln1g = (const float*)d_in[7];
  const float* ln1b = (const float*)d_in[8];
  const float* W1   = (const float*)d_in[9];
  const float* b1   = (const float*)d_in[10];
  const float* W2   = (const float*)d_in[11];
  const float* b2   = (const float*)d_in[12];
  const float* ln2g = (const float*)d_in[13];
  const float* ln2b = (const float*)d_in[14];
  const float* hlng = (const float*)d_in[15];
  const float* hlnb = (const float*)d_in[16];
  const float* hW   = (const float*)d_in[17];
  const float* hb   = (const float*)d_in[18];
  float* out = (float*)d_out;

  char* ws = (char*)d_ws;
  size_t off = 0;
  auto alloc = [&](size_t bytes) {
    char* p = ws + off;
    off = (off + bytes + 255) & ~(size_t)255;
    return p;
  };
  unsigned short* Wqkv_b = (unsigned short*)alloc((size_t)NLAYER*3072*1024*2);
  unsigned short* Wo_b   = (unsigned short*)alloc((size_t)NLAYER*1024*1024*2);
  unsigned short* W1_b   = (unsigned short*)alloc((size_t)NLAYER*4096*1024*2);
  unsigned short* W2_b   = (unsigned short*)alloc((size_t)NLAYER*1024*4096*2);
  float*          X      = (float*)alloc((size_t)TOKENS*1024*4);
  unsigned short* Xb     = (unsigned short*)alloc((size_t)TOKENS*1024*2);
  unsigned short* Qb     = (unsigned short*)alloc((size_t)TOKENS*3072*2);  // qkv bf16
  unsigned short* Vtg    = (unsigned short*)alloc((size_t)TOKENS*1024*2);  // V transposed
  float*          Y      = (float*)alloc((size_t)TOKENS*1024*4);
  unsigned short* Ab     = (unsigned short*)alloc((size_t)TOKENS*1024*2);
  unsigned short* Gb     = Qb;  // FF intermediate (67.1MB) aliases Qb+Vtg (exactly 67.1MB)
  float*          cls    = (float*)alloc(8*1024*4);
  float*          mb     = (float*)alloc(TOKENS*4);

  f2b_kernel<<<2048, 256, 0, stream>>>((const float4*)Wqkv, (ushort4*)Wqkv_b, (long)NLAYER*3072*1024/4);
  f2b_kernel<<<2048, 256, 0, stream>>>((const float4*)Wo,   (ushort4*)Wo_b,   (long)NLAYER*1024*1024/4);
  f2b_kernel<<<2048, 256, 0, stream>>>((const float4*)W1,   (ushort4*)W1_b,   (long)NLAYER*4096*1024/4);
  f2b_kernel<<<2048, 256, 0, stream>>>((const float4*)W2,   (ushort4*)W2_b,   (long)NLAYER*1024*4096/4);
  embed_kernel<<<(TOKENS*256)/256, 256, 0, stream>>>(ids, (const float4*)tok, (const float4*)pos,
                                                     (float4*)X, (ushort4*)Xb);
  maskb_kernel<<<TOKENS/256, 256, 0, stream>>>(ids, mb);

  for (int i = 0; i < NLAYER; ++i) {
    gemm128<3><<<dim3(3072/128, TOKENS/128), 256, 0, stream>>>(
        Xb, Wqkv_b + (size_t)i*3072*1024, bqkv + i*3072, nullptr, Qb, Vtg, TOKENS, 3072, 1024);
    attn2<<<dim3(SEQ_L/64, NHEAD, SEQ_B), 256, 0, stream>>>(Qb, Vtg, mb, Ab);
    gemm128<0><<<dim3(1024/128, TOKENS/128), 256, 0, stream>>>(
        Ab, Wo_b + (size_t)i*1024*1024, bo + i*1024, Y, nullptr, nullptr, TOKENS, 1024, 1024);
    add_ln<<<TOKENS, 256, 0, stream>>>(X, Y, ln1g + i*1024, ln1b + i*1024, X, Xb, 1024L, 1024L);
    gemm128<1><<<dim3(4096/128, TOKENS/128), 256, 0, stream>>>(
        Xb, W1_b + (size_t)i*4096*1024, b1 + i*4096, nullptr, Gb, nullptr, TOKENS, 4096, 1024);
    gemm128<0><<<dim3(1024/128, TOKENS/128), 256, 0, stream>>>(
        Gb, W2_b + (size_t)i*1024*4096, b2 + i*1024, Y, nullptr, nullptr, TOKENS, 1024, 4096);
    add_ln<<<TOKENS, 256, 0, stream>>>(X, Y, ln2g + i*1024, ln2b + i*1024, X, Xb, 1024L, 1024L);
  }
  add_ln<<<8, 256, 0, stream>>>(X, nullptr, hlng, hlnb, cls, nullptr, (long)SEQ_L*1024, 1024L);
  head_kernel<<<dim3(4, 8), 256, 0, stream>>>(cls, hW, hb, out);
}